// Round 1
// baseline (224.020 us; speedup 1.0000x reference)
//
#include <hip/hip_runtime.h>

typedef __bf16 bf16_t;
typedef bf16_t bf16x8 __attribute__((ext_vector_type(8)));
typedef float f32x4 __attribute__((ext_vector_type(4)));

#define NSEQ 2048
#define EMB 512
#define HEADS 8
#define HD 64
#define BATCH 4
#define LOG2E 1.4426950408889634f

// ---------------------------------------------------------------------------
// Projection GEMM: C[8192,512] = x @ W^T + bias, output bf16 into
//   z==0: Kh[b][h][n][d]   (row-major per head)
//   z==1: Vt[b][h][d][n]   (transposed per head, so PV B-frags are contiguous)
// 128x128 tile, BK=32, 4 waves (2x2 of 64x64), 16x16x32 bf16 MFMA.
// ---------------------------------------------------------------------------
__global__ __launch_bounds__(256) void proj_kernel(
    const float* __restrict__ x,
    const float* __restrict__ Wk, const float* __restrict__ bk,
    const float* __restrict__ Wv, const float* __restrict__ bv,
    bf16_t* __restrict__ Kh, bf16_t* __restrict__ Vt)
{
  const int zz = blockIdx.z;
  const float* __restrict__ W    = zz ? Wv : Wk;
  const float* __restrict__ bias = zz ? bv : bk;

  // pitch 40 (+8 pad): row stride 80B = 20 banks -> worst 2-way (free)
  __shared__ __align__(16) bf16_t Al[128][40];
  __shared__ __align__(16) bf16_t Bl[128][40];

  const int t    = threadIdx.x;
  const int w    = t >> 6;
  const int lane = t & 63;
  const int quad = lane >> 4;
  const int l15  = lane & 15;
  const int wr   = w >> 1, wc = w & 1;
  const int m0   = blockIdx.x * 128;
  const int n0   = blockIdx.y * 128;

  const int lrow = t >> 3;        // 0..31
  const int lcol = (t & 7) * 4;   // 0..28 step 4

  f32x4 acc[4][4] = {};

  for (int k0 = 0; k0 < EMB; k0 += 32) {
#pragma unroll
    for (int p = 0; p < 4; ++p) {
      const int r = lrow + p * 32;
      const float4 av  = *(const float4*)(x + (size_t)(m0 + r) * EMB + k0 + lcol);
      const float4 bv4 = *(const float4*)(W + (size_t)(n0 + r) * EMB + k0 + lcol);
      union { bf16_t h[4]; uint2 u; } pa, pb;
      pa.h[0] = (bf16_t)av.x;  pa.h[1] = (bf16_t)av.y;
      pa.h[2] = (bf16_t)av.z;  pa.h[3] = (bf16_t)av.w;
      pb.h[0] = (bf16_t)bv4.x; pb.h[1] = (bf16_t)bv4.y;
      pb.h[2] = (bf16_t)bv4.z; pb.h[3] = (bf16_t)bv4.w;
      *(uint2*)(&Al[r][lcol]) = pa.u;
      *(uint2*)(&Bl[r][lcol]) = pb.u;
    }
    __syncthreads();

    bf16x8 af[4], bfr[4];
#pragma unroll
    for (int mt = 0; mt < 4; ++mt)
      af[mt] = *(const bf16x8*)(&Al[wr * 64 + mt * 16 + l15][quad * 8]);
#pragma unroll
    for (int nt = 0; nt < 4; ++nt)
      bfr[nt] = *(const bf16x8*)(&Bl[wc * 64 + nt * 16 + l15][quad * 8]);
#pragma unroll
    for (int mt = 0; mt < 4; ++mt)
#pragma unroll
      for (int nt = 0; nt < 4; ++nt)
        acc[mt][nt] = __builtin_amdgcn_mfma_f32_16x16x32_bf16(
            af[mt], bfr[nt], acc[mt][nt], 0, 0, 0);
    __syncthreads();
  }

  // Epilogue: +bias, cast bf16, scatter to head layouts.
#pragma unroll
  for (int mt = 0; mt < 4; ++mt) {
#pragma unroll
    for (int nt = 0; nt < 4; ++nt) {
      const int c  = n0 + wc * 64 + nt * 16 + l15;  // 0..511 output feature
      const int hh = c >> 6, d = c & 63;
      const float bb = bias[c];
#pragma unroll
      for (int reg = 0; reg < 4; ++reg) {
        const int r = m0 + wr * 64 + mt * 16 + quad * 4 + reg;  // global row
        const int b = r >> 11, n = r & (NSEQ - 1);
        const float v = acc[mt][nt][reg] + bb;
        if (!zz)
          Kh[(((size_t)(b * HEADS + hh)) * NSEQ + n) * HD + d] = (bf16_t)v;
        else
          Vt[(((size_t)(b * HEADS + hh)) * HD + d) * NSEQ + n] = (bf16_t)v;
      }
    }
  }
}

// ---------------------------------------------------------------------------
// Flash attention, Q = K. One block = one (b,h) x 128 Q-rows; 4 independent
// waves x 32 rows. K/Q/V fragments loaded straight from global (L2) in MFMA
// fragment order; only P round-trips through per-wave LDS (C->A relayout).
// Post-softmax scale 1/sqrt(512) applied in epilogue.
// ---------------------------------------------------------------------------
__global__ __launch_bounds__(256) void flash_kernel(
    const bf16_t* __restrict__ Kh, const bf16_t* __restrict__ Vt,
    float* __restrict__ out)
{
  // pitch 72: row stride 144B -> write quads 2-way, b128 reads 2-way (free)
  __shared__ __align__(16) bf16_t Pl[4][32][72];

  const int t    = threadIdx.x;
  const int w    = t >> 6;
  const int lane = t & 63;
  const int quad = lane >> 4;
  const int l15  = lane & 15;

  const int bh = blockIdx.x;           // 0..31
  const int b  = bh >> 3, h = bh & 7;
  const int mtile = blockIdx.y;        // 0..15

  const bf16_t* __restrict__ Kb = Kh + (size_t)bh * NSEQ * HD;
  const bf16_t* __restrict__ Vb = Vt + (size_t)bh * HD * NSEQ;

  const int rowbase = mtile * 128 + w * 32;  // first Q row of this wave

  // Q fragments (A-layout), resident whole kernel
  bf16x8 qf[2][2];
#pragma unroll
  for (int mt = 0; mt < 2; ++mt)
#pragma unroll
    for (int kk = 0; kk < 2; ++kk)
      qf[mt][kk] = *(const bf16x8*)(Kb + (size_t)(rowbase + mt * 16 + l15) * HD +
                                    kk * 32 + quad * 8);

  f32x4 acco[2][4] = {};
  float mrow[2][4], lrow[2][4];
#pragma unroll
  for (int mt = 0; mt < 2; ++mt)
#pragma unroll
    for (int reg = 0; reg < 4; ++reg) { mrow[mt][reg] = -INFINITY; lrow[mt][reg] = 0.f; }

  for (int kt = 0; kt < NSEQ / 64; ++kt) {
    const bf16_t* Kt = Kb + (size_t)kt * 64 * HD;

    // S = Q K^T  (B-frag of K^T == A-frag pattern on row-major K)
    bf16x8 kf[4][2];
#pragma unroll
    for (int nt = 0; nt < 4; ++nt)
#pragma unroll
      for (int kk = 0; kk < 2; ++kk)
        kf[nt][kk] = *(const bf16x8*)(Kt + (size_t)(nt * 16 + l15) * HD +
                                      kk * 32 + quad * 8);
    f32x4 s[2][4] = {};
#pragma unroll
    for (int mt = 0; mt < 2; ++mt)
#pragma unroll
      for (int nt = 0; nt < 4; ++nt) {
        s[mt][nt] = __builtin_amdgcn_mfma_f32_16x16x32_bf16(qf[mt][0], kf[nt][0], s[mt][nt], 0, 0, 0);
        s[mt][nt] = __builtin_amdgcn_mfma_f32_16x16x32_bf16(qf[mt][1], kf[nt][1], s[mt][nt], 0, 0, 0);
      }

    // Online softmax per row (row r lives in lanes sharing quad, reg = r&3)
#pragma unroll
    for (int mt = 0; mt < 2; ++mt) {
      float mc[4];
#pragma unroll
      for (int reg = 0; reg < 4; ++reg)
        mc[reg] = fmaxf(fmaxf(s[mt][0][reg], s[mt][1][reg]),
                        fmaxf(s[mt][2][reg], s[mt][3][reg]));
#pragma unroll
      for (int off = 8; off >= 1; off >>= 1)
#pragma unroll
        for (int reg = 0; reg < 4; ++reg)
          mc[reg] = fmaxf(mc[reg], __shfl_xor(mc[reg], off, 64));

      float al[4];
#pragma unroll
      for (int reg = 0; reg < 4; ++reg) {
        const float mn = fmaxf(mrow[mt][reg], mc[reg]);
        al[reg] = __builtin_amdgcn_exp2f((mrow[mt][reg] - mn) * LOG2E);
        mrow[mt][reg] = mn;
      }
#pragma unroll
      for (int nt = 0; nt < 4; ++nt)
#pragma unroll
        for (int reg = 0; reg < 4; ++reg)
          s[mt][nt][reg] = __builtin_amdgcn_exp2f((s[mt][nt][reg] - mrow[mt][reg]) * LOG2E);

      float rs[4];
#pragma unroll
      for (int reg = 0; reg < 4; ++reg)
        rs[reg] = (s[mt][0][reg] + s[mt][1][reg]) + (s[mt][2][reg] + s[mt][3][reg]);
#pragma unroll
      for (int off = 8; off >= 1; off >>= 1)
#pragma unroll
        for (int reg = 0; reg < 4; ++reg)
          rs[reg] += __shfl_xor(rs[reg], off, 64);
#pragma unroll
      for (int reg = 0; reg < 4; ++reg)
        lrow[mt][reg] = lrow[mt][reg] * al[reg] + rs[reg];

      // rescale O accumulator
#pragma unroll
      for (int dt = 0; dt < 4; ++dt)
#pragma unroll
        for (int reg = 0; reg < 4; ++reg)
          acco[mt][dt][reg] *= al[reg];

      // P -> LDS (C-layout scatter), per-wave private region, no barrier
#pragma unroll
      for (int nt = 0; nt < 4; ++nt)
#pragma unroll
        for (int reg = 0; reg < 4; ++reg)
          Pl[w][mt * 16 + quad * 4 + reg][nt * 16 + l15] = (bf16_t)s[mt][nt][reg];
    }

    // O += P V  (P read back in A-layout; V^T B-frags contiguous from global)
#pragma unroll
    for (int kk = 0; kk < 2; ++kk) {
      bf16x8 vfs[4];
#pragma unroll
      for (int dt = 0; dt < 4; ++dt)
        vfs[dt] = *(const bf16x8*)(Vb + (size_t)(dt * 16 + l15) * NSEQ +
                                   kt * 64 + kk * 32 + quad * 8);
#pragma unroll
      for (int mt = 0; mt < 2; ++mt) {
        const bf16x8 pf = *(const bf16x8*)(&Pl[w][mt * 16 + l15][kk * 32 + quad * 8]);
#pragma unroll
        for (int dt = 0; dt < 4; ++dt)
          acco[mt][dt] = __builtin_amdgcn_mfma_f32_16x16x32_bf16(pf, vfs[dt], acco[mt][dt], 0, 0, 0);
      }
    }
  }

  // Epilogue: out[b][n][h*64+d] = O / l * (1/sqrt(512))
  const float SCL = 0.044194173824159216f;
#pragma unroll
  for (int mt = 0; mt < 2; ++mt)
#pragma unroll
    for (int dt = 0; dt < 4; ++dt) {
      const int d = dt * 16 + l15;
#pragma unroll
      for (int reg = 0; reg < 4; ++reg) {
        const int n = rowbase + mt * 16 + quad * 4 + reg;
        const float f = SCL / lrow[mt][reg];
        out[((size_t)(b * NSEQ + n)) * EMB + h * HD + d] = acco[mt][dt][reg] * f;
      }
    }
}

extern "C" void kernel_launch(void* const* d_in, const int* in_sizes, int n_in,
                              void* d_out, int out_size, void* d_ws, size_t ws_size,
                              hipStream_t stream) {
  const float* x  = (const float*)d_in[0];
  const float* Wk = (const float*)d_in[1];
  const float* bk = (const float*)d_in[2];
  const float* Wv = (const float*)d_in[3];
  const float* bv = (const float*)d_in[4];
  float* out = (float*)d_out;

  bf16_t* Kh = (bf16_t*)d_ws;                                   // 8 MB
  bf16_t* Vt = Kh + (size_t)BATCH * HEADS * NSEQ * HD;          // 8 MB

  dim3 pg(8192 / 128, EMB / 128, 2);
  proj_kernel<<<pg, 256, 0, stream>>>(x, Wk, bk, Wv, bv, Kh, Vt);

  dim3 fg(BATCH * HEADS, NSEQ / 128);
  flash_kernel<<<fg, 256, 0, stream>>>(Kh, Vt, out);
}